// Round 14
// baseline (316.918 us; speedup 1.0000x reference)
//
#include <hip/hip_runtime.h>
#include <hip/hip_bf16.h>
#include <math.h>

#define QN 128
#define TN 48
#define CN 64
#define HN 96
#define WN 128
#define DN 128
#define KK 49
#define IN_DIM 276
#define XPAD 288
#define NROWS (QN*TN)
#define PI_F 3.14159265358979323846f

typedef __hip_bfloat16 bf16;
typedef unsigned short u16;
using bf16x8 = __attribute__((ext_vector_type(8))) short;
using f32x4  = __attribute__((ext_vector_type(4))) float;

__device__ inline float fixnan(float x){ return (x == x && fabsf(x) < 1e30f) ? x : 0.f; }

template<int MODE> __device__ inline float ld(const void* p, size_t i){
  if constexpr (MODE == 0) return ((const float*)p)[i];
  else {
    unsigned int u = ((const unsigned short*)p)[i];
    return __uint_as_float(u << 16);
  }
}

__device__ inline short f2b(float x){
  __hip_bfloat16 h = __float2bfloat16(x);
  return *reinterpret_cast<short*>(&h);
}
__device__ inline float b2f16(u16 u){ return __uint_as_float(((unsigned int)u) << 16); }

// inline dtype detect: 1 = bf16 buffers, 0 = f32 buffers. Wave-uniform, deterministic.
__device__ inline int detect_mode(const void* query){
  const u16* q = (const u16*)query;
  int lane = threadIdx.x & 63;
  float v = b2f16(q[lane]);
  float a = fabsf(v);
  unsigned long long m = __ballot(a > 1e-3f && a < 30.f);
  return (__popcll(m) >= 48) ? 1 : 0;
}

__device__ inline float waveReduceSum(float v){
  #pragma unroll
  for (int off = 32; off > 0; off >>= 1) v += __shfl_xor(v, off, 64);
  return v;
}

__device__ inline float gelu_exact(float x){
  return 0.5f * x * (1.f + erff(x * 0.70710678118654752440f));
}

__device__ inline f32x4 mfma16(bf16x8 a, bf16x8 b, f32x4 c){
  return __builtin_amdgcn_mfma_f32_16x16x32_bf16(a, b, c, 0, 0, 0);
}

__device__ inline float decode_stride(const void* p){
  int iv = *(const int*)p;
  if (iv >= 1 && iv <= (1 << 20)) return (float)iv;
  float fv = __int_as_float(iv);
  if (fv == fv && fv >= 0.25f && fv <= 1048576.f) return fv;
  unsigned int lo = ((unsigned int)(*(const unsigned short*)p)) << 16;
  float bv = __uint_as_float(lo);
  if (bv == bv && bv >= 0.25f && bv <= 1048576.f) return bv;
  return 4.f;
}

__device__ inline void bput(short* base, int stride_sh, int r, int k, float v){
  *(short*)((char*)base + (size_t)r*stride_sh*2 + ((2*k) ^ ((r & 7) << 4))) = f2b(v);
}
__device__ inline float bget(const short* base, int stride_sh, int r, int k){
  unsigned short u = *(const unsigned short*)((const char*)base + (size_t)r*stride_sh*2 + ((2*k) ^ ((r & 7) << 4)));
  return __uint_as_float(((unsigned int)u) << 16);
}
__device__ inline bf16x8 bget8(const short* base, int stride_sh, int r, int k0){
  return *(const bf16x8*)((const char*)base + (size_t)r*stride_sh*2 + ((2*k0) ^ ((r & 7) << 4)));
}

struct SLds {
  float sc0[32], sc1[32];
  float qv[CN];
  float hdl[32][132];
  union {
    short Xs[32][320];
    struct { short hn[32][128]; short hn2[32][128]; short y1[32][256]; } b;
    float dots[32][64];
  } u;
};

// ---- weight transpose sizes ----
#define TW_PW   (128*XPAD)
#define TW_W1   (4*256*128)
#define TW_W2   (4*128*256)
#define TW_VW1  (64*128)
#define TW_TOT  (TW_PW + TW_W1 + TW_W2 + TW_VW1)
#define NB_TW   ((TW_TOT + 255)/256)
#define NB_INIT ((NROWS + 255)/256)
#define NB_TRANS (TN*HN)

template<int MODE>
__device__ void transW_item(int idx, const void* pw, const void* w1, const void* w2,
                            const void* vw1,
                            bf16* pwt, bf16* w1t, bf16* w2t, bf16* vw1t){
  if (idx < TW_PW){
    int n = idx / XPAD, kk = idx % XPAD;
    float v = (kk < IN_DIM) ? ld<MODE>(pw, (size_t)kk*DN + n) : 0.f;
    ((short*)pwt)[idx] = f2b(v);
  } else if (idx < TW_PW + TW_W1){
    int i2 = idx - TW_PW;
    int k = i2 & 127, n = (i2 >> 7) & 255, l = i2 >> 15;
    ((short*)w1t)[i2] = f2b(ld<MODE>(w1, (size_t)l*32768 + (size_t)k*256 + n));
  } else if (idx < TW_PW + TW_W1 + TW_W2){
    int i3 = idx - TW_PW - TW_W1;
    int k = i3 & 255, n = (i3 >> 8) & 127, l = i3 >> 15;
    ((short*)w2t)[i3] = f2b(ld<MODE>(w2, (size_t)l*32768 + (size_t)k*128 + n));
  } else {
    int i4 = idx - TW_PW - TW_W1 - TW_W2;
    int n = i4 >> 7, k = i4 & 127;
    ((short*)vw1t)[i4] = f2b(ld<MODE>(vw1, (size_t)k*64 + n));
  }
}

template<int MODE>
__device__ void setup_body(u16 (*tile)[130], int bid,
    const void* ct, const void* query, const void* fmap,
    const void* pw, const void* w1, const void* w2, const void* vw1,
    float* tracks, float* vis_sum,
    bf16* pwt, bf16* w1t, bf16* w2t, bf16* vw1t, u16* fmapT){
  int tid = threadIdx.x;
  if (bid < NB_TW){
    int idx = bid*256 + tid;
    if (idx < TW_TOT) transW_item<MODE>(idx, pw, w1, w2, vw1, pwt, w1t, w2t, vw1t);
  } else if (bid < NB_TW + NB_INIT){
    int i = (bid - NB_TW)*256 + tid;
    if (i < NROWS){
      tracks[2*i]   = fixnan(ld<MODE>(ct, 2*i));
      tracks[2*i+1] = fixnan(ld<MODE>(ct, 2*i+1));
      vis_sum[i] = 0.f;
    }
  } else {
    int tb = bid - NB_TW - NB_INIT;
    int t = tb / HN, y = tb % HN;
    int wv = tid >> 6, lane = tid & 63;
    #pragma unroll 4
    for (int ci = 0; ci < 16; ++ci){
      int c = ci*4 + wv;
      size_t base = (((size_t)t*CN + c)*HN + y)*WN;
      if constexpr (MODE == 1){
        const u16* fp = (const u16*)fmap + base + 2*lane;
        tile[c][2*lane]   = fp[0];
        tile[c][2*lane+1] = fp[1];
      } else {
        const float* fp = (const float*)fmap + base + 2*lane;
        tile[c][2*lane]   = (u16)f2b(fp[0]);
        tile[c][2*lane+1] = (u16)f2b(fp[1]);
      }
    }
    __syncthreads();
    u16* op = fmapT + (((size_t)t*HN + y)*WN)*CN + lane;
    #pragma unroll 4
    for (int xi = 0; xi < 32; ++xi){
      int x = xi*4 + wv;
      op[(size_t)x*CN] = tile[lane][x];
    }
  }
}
__global__ __launch_bounds__(256) void k_setup(
    const void* ct, const void* query, const void* fmap,
    const void* pw, const void* w1, const void* w2, const void* vw1,
    float* tracks, float* vis_sum,
    bf16* pwt, bf16* w1t, bf16* w2t, bf16* vw1t, u16* fmapT){
  __shared__ u16 tile[64][130];
  if (detect_mode(query) == 0)
    setup_body<0>(tile, blockIdx.x, ct, query, fmap, pw, w1, w2, vw1,
                  tracks, vis_sum, pwt, w1t, w2t, vw1t, fmapT);
  else
    setup_body<1>(tile, blockIdx.x, ct, query, fmap, pw, w1, w2, vw1,
                  tracks, vis_sum, pwt, w1t, w2t, vw1t, fmapT);
}

// ==== standalone corr (slow path only) ====
template<int MODE>
__device__ void corr_impl(float* qv, float* dots,
    const void* fmap, const void* query, const void* stride_p,
    const float* __restrict__ tr, short* __restrict__ Xc)
{
  int blk = blockIdx.x;
  int q = blk / TN, t = blk % TN;
  int ll = threadIdx.x;
  qv[ll] = ld<MODE>(query, q*CN + ll);
  float fs = decode_stride(stride_p);
  float c0 = fixnan(tr[2*blk]), c1 = fixnan(tr[2*blk+1]);
  float px = fminf(fmaxf(c0 / fs, -1e6f), 1e6f);
  float py = fminf(fmaxf(c1 / fs, -1e6f), 1e6f);
  float fx0 = floorf(px), fy0 = floorf(py);
  float dx = px - fx0, dy = py - fy0;
  __syncthreads();

  int bx = (int)fx0, by = (int)fy0;
  int j = ll >> 3, i = ll & 7;
  int xi = bx + i - 3, yi = by + j - 3;
  float dot = 0.f;
  if (xi >= 0 && xi < WN && yi >= 0 && yi < HN){
    size_t base = ((size_t)t*CN)*HN*WN + (size_t)yi*WN + xi;
    #pragma unroll 8
    for (int c = 0; c < CN; ++c)
      dot += qv[c] * ld<MODE>(fmap, base + (size_t)c*HN*WN);
  }
  dots[j*8 + i] = dot;
  __syncthreads();

  if (ll < KK){
    int oy = ll / 7, ox = ll % 7;
    float v = (1.f-dx)*(1.f-dy)*dots[oy*8+ox]   + dx*(1.f-dy)*dots[oy*8+ox+1]
            + (1.f-dx)*dy*dots[(oy+1)*8+ox]     + dx*dy*dots[(oy+1)*8+ox+1];
    Xc[(size_t)blk*64 + ll] = f2b(fixnan(v));
  }
}
__global__ __launch_bounds__(64) void k_corr(
    const void* fmap, const void* query, const void* stride_p,
    const float* tr, short* Xc)
{
  __shared__ float qv[CN];
  __shared__ float dots[64];
  if (detect_mode(query) == 0) corr_impl<0>(qv, dots, fmap, query, stride_p, tr, Xc);
  else                         corr_impl<1>(qv, dots, fmap, query, stride_p, tr, Xc);
}

// per-wave fast corr for row r: dots scratch in 'dots' (64 floats), writes Xs cols 0..48
template<int DST_XS>
__device__ inline void wave_corr_row(SLds& s, const u16* __restrict__ fmapT,
    int t, int r, int ll, float fs, const float* qv8, short* __restrict__ XcW, int grow){
  float* dots = DST_XS ? &s.hdl[r][0] : &s.u.dots[r][0];
  float px = fminf(fmaxf(s.sc0[r] / fs, -1e6f), 1e6f);
  float py = fminf(fmaxf(s.sc1[r] / fs, -1e6f), 1e6f);
  float fx0 = floorf(px), fy0 = floorf(py);
  float dx = px - fx0, dy = py - fy0;
  int x0 = (int)fx0 - 3, y0 = (int)fy0 - 3;
  dots[ll] = 0.f;
  if (x0 <= 127 && x0 + 7 >= 0){
    int x0c = min(max(x0, 0), WN - 8);
    int sh = x0c - x0;
    int i = (ll >> 3) + sh;
    bool wr = ((ll & 7) == 0) && (i >= 0) && (i < 8);
    #pragma unroll
    for (int j = 0; j < 8; ++j){
      int yj = y0 + j;
      if (yj < 0 || yj >= HN) continue;
      const u16* blkp = fmapT + ((((size_t)t*HN + yj)*WN + x0c) << 6);
      bf16x8 v = *(const bf16x8*)(blkp + ll*8);
      float p = 0.f;
      #pragma unroll
      for (int u = 0; u < 8; ++u) p += qv8[u] * b2f16((u16)v[u]);
      p += __shfl_xor(p, 1, 64);
      p += __shfl_xor(p, 2, 64);
      p += __shfl_xor(p, 4, 64);
      if (wr) dots[j*8 + i] = p;
    }
  }
  if (ll < KK){
    int oy = ll / 7, ox = ll % 7;
    float v = (1.f-dx)*(1.f-dy)*dots[oy*8+ox]   + dx*(1.f-dy)*dots[oy*8+ox+1]
            + (1.f-dx)*dy*dots[(oy+1)*8+ox]     + dx*dy*dots[(oy+1)*8+ox+1];
    if constexpr (DST_XS) bput(&s.u.Xs[0][0], 320, r, ll, fixnan(v));
    else                  XcW[(size_t)grow*64 + ll] = f2b(fixnan(v));
  }
}

// ==== fused trunk: block=(q, t-half); 32 rows, 16 waves ====
template<int MODE, int TAIL, int FIRST, int ICORR>
__device__ void iter_impl(SLds& s,
    const u16* __restrict__ fmapT, const void* query, const void* stride_p,
    const short* __restrict__ XcR, short* __restrict__ XcW,
    const float* __restrict__ tr_in, float* __restrict__ tr_out,
    const float* __restrict__ vi_in, float* __restrict__ vi_out,
    const float* __restrict__ hd_in, float* __restrict__ hd_out,
    const bf16* pwt, const void* pb,
    const void* ln1g, const void* ln1b, const void* cw, const void* cb,
    const void* ln2g, const void* ln2b,
    const bf16* w1t, const void* b1, const bf16* w2t, const void* b2,
    const void* dwp, const void* dbp,
    const bf16* vw1t, const void* vb1, const void* vw2, const void* vb2,
    void* out, int last)
{
  int bid = blockIdx.x;
  int q = bid >> 1, half = bid & 1, T0 = half * 16;
  int tid = threadIdx.x, wv = tid >> 6, ll = tid & 63;
  int R0 = q*TN + T0;
  float fs = decode_stride(stride_p);

  if (tid < 32){
    s.sc0[tid] = fixnan(tr_in[2*(R0 + tid)]);
    s.sc1[tid] = fixnan(tr_in[2*(R0 + tid) + 1]);
  }
  if (tid >= 64 && tid < 128) s.qv[tid - 64] = ld<MODE>(query, q*CN + (tid - 64));
  __syncthreads();

  // ---- corr columns of X: inline (iter 0 fast) or from Xc ----
  if constexpr (ICORR){
    float qv8[8];
    #pragma unroll
    for (int u = 0; u < 8; ++u) qv8[u] = s.qv[(ll & 7)*8 + u];
    #pragma unroll
    for (int rr = 0; rr < 2; ++rr){
      int r = wv*2 + rr;
      wave_corr_row<1>(s, fmapT, T0 + r, r, ll, fs, qv8, nullptr, 0);
    }
  } else {
    for (int idx = tid; idx < 32*KK; idx += 1024){
      int r = idx / KK, kk = idx % KK;
      bput(&s.u.Xs[0][0], 320, r, kk, b2f16((u16)XcR[(size_t)(R0 + r)*64 + kk]));
    }
  }
  // ---- rest of assemble ----
  for (int idx = tid; idx < 32*3; idx += 1024){
    int r = idx / 3, cd = idx % 3;
    float v = (cd == 0) ? s.sc0[r] : (cd == 1 ? s.sc1[r] : (float)(T0+r)/(float)(TN-1));
    bput(&s.u.Xs[0][0], 320, r, KK + cd, v);
  }
  for (int idx = tid; idx < 32*96; idx += 1024){
    int r = idx / 96, j = idx % 96, coord = j >> 5, rm = j & 31, band = rm & 15;
    float cv = (coord == 0) ? s.sc0[r] : (coord == 1 ? s.sc1[r] : (float)(T0+r)/(float)(TN-1));
    float a = cv * exp2f(0.6f*(float)band) * PI_F;
    float v = (rm < 16) ? __sinf(a) : __cosf(a);
    bput(&s.u.Xs[0][0], 320, r, KK + 3 + coord*32 + rm, fixnan(v));
  }
  if constexpr (FIRST){
    for (int idx = tid; idx < 32*DN; idx += 1024){
      int r = idx >> 7, d = idx & 127;
      bput(&s.u.Xs[0][0], 320, r, 148 + d, 0.f);
    }
  } else {
    for (int idx = tid; idx < 32*32; idx += 1024){
      int r = idx >> 5, d4 = (idx & 31)*4;
      f32x4 hv = *(const f32x4*)(hd_in + (size_t)(R0 + r)*DN + d4);
      #pragma unroll
      for (int u = 0; u < 4; ++u)
        bput(&s.u.Xs[0][0], 320, r, 148 + d4 + u, fixnan(hv[u]));
    }
  }
  for (int idx = tid; idx < 32*12; idx += 1024){
    int r = idx / 12, p = idx % 12;
    bput(&s.u.Xs[0][0], 320, r, IN_DIM + p, 0.f);
  }
  __syncthreads();

  // ---- proj MFMA: 1 tile/wave ----
  {
    int rA = ll & 15, gK = ll >> 4;
    int rt = wv & 1, nt = wv >> 1;
    bf16x8 afr[9];
    #pragma unroll
    for (int ks = 0; ks < 9; ++ks)
      afr[ks] = bget8(&s.u.Xs[0][0], 320, rt*16 + rA, ks*32 + gK*8);
    float bv = ld<MODE>(pb, nt*16 + rA);
    f32x4 acc = {bv, bv, bv, bv};
    #pragma unroll
    for (int ks = 0; ks < 9; ++ks)
      acc = mfma16(afr[ks],
        *(const bf16x8*)((const short*)pwt + (size_t)(nt*16 + rA)*XPAD + ks*32 + gK*8), acc);
    #pragma unroll
    for (int r2 = 0; r2 < 4; ++r2)
      s.hdl[rt*16 + gK*4 + r2][nt*16 + rA] = fixnan(acc[r2]);
  }

  // ---- 4 transformer blocks ----
  #pragma unroll 1
  for (int L = 0; L < 4; ++L){
    float cwr0[5], cwr1[5];
    #pragma unroll
    for (int k = 0; k < 5; ++k){
      cwr0[k] = ld<MODE>(cw, ((size_t)L*DN + ll)*5 + k);
      cwr1[k] = ld<MODE>(cw, ((size_t)L*DN + ll + 64)*5 + k);
    }
    float cbv0 = ld<MODE>(cb, L*DN + ll), cbv1 = ld<MODE>(cb, L*DN + ll + 64);
    float g20 = ld<MODE>(ln2g, L*DN + ll), g21 = ld<MODE>(ln2g, L*DN + ll + 64);
    float c20 = ld<MODE>(ln2b, L*DN + ll), c21 = ld<MODE>(ln2b, L*DN + ll + 64);
    __syncthreads();
    // LN1 -> hn
    {
      float g0 = ld<MODE>(ln1g, L*DN + ll), g1 = ld<MODE>(ln1g, L*DN + ll + 64);
      float b0 = ld<MODE>(ln1b, L*DN + ll), b1v = ld<MODE>(ln1b, L*DN + ll + 64);
      #pragma unroll
      for (int rr = 0; rr < 2; ++rr){
        int r = wv*2 + rr;
        float a0 = s.hdl[r][ll], a1 = s.hdl[r][ll+64];
        float su = waveReduceSum(a0 + a1);
        float sq = waveReduceSum(a0*a0 + a1*a1);
        float m = su * (1.f/128.f);
        float var = fmaxf(sq * (1.f/128.f) - m*m, 0.f);
        float inv = rsqrtf(var + 1e-5f);
        bput(&s.u.b.hn[0][0], 128, r, ll,      (a0 - m)*inv*g0 + b0);
        bput(&s.u.b.hn[0][0], 128, r, ll + 64, (a1 - m)*inv*g1 + b1v);
      }
    }
    __syncthreads();
    // conv + residual + LN2 (registers) -> hdl, hn2
    #pragma unroll
    for (int rr = 0; rr < 2; ++rr){
      int r = wv*2 + rr, t = T0 + r;
      float a0 = cbv0, a1 = cbv1;
      #pragma unroll
      for (int k = 0; k < 5; ++k){
        int tg = t + k - 2, tl = r + k - 2;
        if (tg >= 0 && tg < TN && tl >= 0 && tl < 32){
          a0 += bget(&s.u.b.hn[0][0], 128, tl, ll)      * cwr0[k];
          a1 += bget(&s.u.b.hn[0][0], 128, tl, ll + 64) * cwr1[k];
        }
      }
      float x0 = fixnan(s.hdl[r][ll] + a0);
      float x1 = fixnan(s.hdl[r][ll+64] + a1);
      s.hdl[r][ll] = x0; s.hdl[r][ll+64] = x1;
      float su = waveReduceSum(x0 + x1);
      float sq = waveReduceSum(x0*x0 + x1*x1);
      float m = su * (1.f/128.f);
      float var = fmaxf(sq * (1.f/128.f) - m*m, 0.f);
      float inv = rsqrtf(var + 1e-5f);
      bput(&s.u.b.hn2[0][0], 128, r, ll,      (x0 - m)*inv*g20 + c20);
      bput(&s.u.b.hn2[0][0], 128, r, ll + 64, (x1 - m)*inv*g21 + c21);
    }
    __syncthreads();
    // GEMM1: hn2 @ w1 -> gelu -> y1
    {
      int rA = ll & 15, gK = ll >> 4;
      int rt = wv & 1, nt0 = wv >> 1;
      const short* w1s = (const short*)w1t + (size_t)L*32768;
      bf16x8 afr[4];
      #pragma unroll
      for (int ks = 0; ks < 4; ++ks)
        afr[ks] = bget8(&s.u.b.hn2[0][0], 128, rt*16 + rA, ks*32 + gK*8);
      #pragma unroll
      for (int h = 0; h < 2; ++h){
        int nt = nt0 + h*8;
        float bv = ld<MODE>(b1, L*256 + nt*16 + rA);
        f32x4 acc = {bv, bv, bv, bv};
        #pragma unroll
        for (int ks = 0; ks < 4; ++ks)
          acc = mfma16(afr[ks],
            *(const bf16x8*)(w1s + (size_t)(nt*16 + rA)*DN + ks*32 + gK*8), acc);
        #pragma unroll
        for (int r2 = 0; r2 < 4; ++r2)
          bput(&s.u.b.y1[0][0], 256, rt*16 + gK*4 + r2, nt*16 + rA, gelu_exact(acc[r2]));
      }
    }
    __syncthreads();
    // GEMM2: y1 @ w2 + residual -> hdl (and hn as bf16 when L==3, feeding vis MFMA)
    {
      int rA = ll & 15, gK = ll >> 4;
      int rt = wv & 1, nt = wv >> 1;
      const short* w2s = (const short*)w2t + (size_t)L*32768;
      bf16x8 afr[8];
      #pragma unroll
      for (int ks = 0; ks < 8; ++ks)
        afr[ks] = bget8(&s.u.b.y1[0][0], 256, rt*16 + rA, ks*32 + gK*8);
      float bv = ld<MODE>(b2, L*DN + nt*16 + rA);
      f32x4 acc = {bv, bv, bv, bv};
      #pragma unroll
      for (int ks = 0; ks < 8; ++ks)
        acc = mfma16(afr[ks],
          *(const bf16x8*)(w2s + (size_t)(nt*16 + rA)*256 + ks*32 + gK*8), acc);
      #pragma unroll
      for (int r2 = 0; r2 < 4; ++r2){
        int r = rt*16 + gK*4 + r2, cc = nt*16 + rA;
        float x = fixnan(s.hdl[r][cc] + acc[r2]);
        s.hdl[r][cc] = x;
        if (L == 3) bput(&s.u.b.hn[0][0], 128, r, cc, x);
      }
    }
  }
  __syncthreads();

  // ---- heads: vis MFMA directly from hn (written by GEMM2 L=3) ----
  float* gC = (float*)&s.u.b.y1[0][0];   // [32][72] f32
  {
    int rA = ll & 15, gK = ll >> 4;
    int rt = wv & 1, nt = wv >> 1;
    if (nt < 4){
      float bv = ld<MODE>(vb1, nt*16 + rA);
      f32x4 acc = {bv, bv, bv, bv};
      #pragma unroll
      for (int ks = 0; ks < 4; ++ks)
        acc = mfma16(bget8(&s.u.b.hn[0][0], 128, rt*16 + rA, ks*32 + gK*8),
                     *(const bf16x8*)((const short*)vw1t + (size_t)(nt*16 + rA)*128 + ks*32 + gK*8), acc);
      #pragma unroll
      for (int r2 = 0; r2 < 4; ++r2)
        gC[(rt*16 + gK*4 + r2)*72 + nt*16 + rA] = gelu_exact(acc[r2]);
    }
  }
  __syncthreads();
  float vw2v = ld<MODE>(vw2, ll);
  float dwa = ld<MODE>(dwp, ll*2),     dwb = ld<MODE>(dwp, (ll+64)*2);
  float dwc = ld<MODE>(dwp, ll*2 + 1), dwd = ld<MODE>(dwp, (ll+64)*2 + 1);
  #pragma unroll
  for (int rr = 0; rr < 2; ++rr){
    int r = wv*2 + rr, t = T0 + r, grow = q*TN + t;
    bool owned = half ? (r >= 8) : (r < 24);
    float vis = waveReduceSum(gC[r*72 + ll] * vw2v);
    float x0 = s.hdl[r][ll], x1 = s.hdl[r][ll+64];
    float dX = waveReduceSum(x0*dwa + x1*dwb);
    float dY = waveReduceSum(x0*dwc + x1*dwd);
    if (owned){
      hd_out[(size_t)grow*DN + ll]      = fixnan(x0);
      hd_out[(size_t)grow*DN + ll + 64] = fixnan(x1);
      if (ll == 0){
        float tx = fixnan(tr_in[2*grow]   + dX + ld<MODE>(dbp, 0));
        float ty = fixnan(tr_in[2*grow+1] + dY + ld<MODE>(dbp, 1));
        tr_out[2*grow] = tx; tr_out[2*grow+1] = ty;
        s.sc0[r] = tx; s.sc1[r] = ty;
        float vs = fixnan(vi_in[grow] + vis + ld<MODE>(vb2, 0));
        vi_out[grow] = vs;
        if (last){
          if constexpr (MODE == 0){
            ((float*)out)[grow*3 + 0] = tx;
            ((float*)out)[grow*3 + 1] = ty;
            ((float*)out)[grow*3 + 2] = vs * 0.25f;
          } else {
            ((bf16*)out)[grow*3 + 0] = __float2bfloat16(tx);
            ((bf16*)out)[grow*3 + 1] = __float2bfloat16(ty);
            ((bf16*)out)[grow*3 + 2] = __float2bfloat16(vs * 0.25f);
          }
        }
      }
    }
  }

  // ---- tail corr for next iteration ----
  if constexpr (TAIL){
    if (!last){
      __syncthreads();
      float qv8[8];
      #pragma unroll
      for (int u = 0; u < 8; ++u) qv8[u] = s.qv[(ll & 7)*8 + u];
      #pragma unroll
      for (int rr = 0; rr < 2; ++rr){
        int r = wv*2 + rr, t = T0 + r, grow = q*TN + t;
        bool owned = half ? (r >= 8) : (r < 24);
        if (!owned) continue;
        wave_corr_row<0>(s, fmapT, t, r, ll, fs, qv8, XcW, grow);
      }
    }
  }
}

template<int TAIL, int FIRST, int ICORR>
__global__ __launch_bounds__(1024, 1) void k_iter(
    const u16* fmapT, const void* query, const void* stride_p,
    const short* XcR, short* XcW,
    const float* tr_in, float* tr_out, const float* vi_in, float* vi_out,
    const float* hd_in, float* hd_out,
    const bf16* pwt, const void* pb,
    const void* ln1g, const void* ln1b, const void* cw, const void* cb,
    const void* ln2g, const void* ln2b,
    const bf16* w1t, const void* b1, const bf16* w2t, const void* b2,
    const void* dwp, const void* dbp,
    const bf16* vw1t, const void* vb1, const void* vw2, const void* vb2,
    void* out, int last)
{
  __shared__ SLds s;
  if (detect_mode(query) == 0)
    iter_impl<0, TAIL, FIRST, ICORR>(s, fmapT, query, stride_p, XcR, XcW, tr_in, tr_out, vi_in, vi_out,
                 hd_in, hd_out, pwt, pb, ln1g, ln1b, cw, cb, ln2g, ln2b, w1t, b1, w2t, b2,
                 dwp, dbp, vw1t, vb1, vw2, vb2, out, last);
  else
    iter_impl<1, TAIL, FIRST, ICORR>(s, fmapT, query, stride_p, XcR, XcW, tr_in, tr_out, vi_in, vi_out,
                 hd_in, hd_out, pwt, pb, ln1g, ln1b, cw, cb, ln2g, ln2b, w1t, b1, w2t, b2,
                 dwp, dbp, vw1t, vb1, vw2, vb2, out, last);
}

extern "C" void kernel_launch(void* const* d_in, const int* in_sizes, int n_in,
                              void* d_out, int out_size, void* d_ws, size_t ws_size,
                              hipStream_t stream) {
  const void* ct    = d_in[0];
  const void* query = d_in[1];
  const void* fmap  = d_in[2];
  const void* fs    = d_in[3];
  const void* pw    = d_in[4];
  const void* pb    = d_in[5];
  const void* ln1g  = d_in[6];
  const void* ln1b  = d_in[7];
  const void* cw    = d_in[8];
  const void* cb    = d_in[9];
  const void* ln2g  = d_in[10];
  const void* ln2b  = d_in[11];
  const void* w1    = d_in[12];
  const void* b1    = d_in[13];
  const void* w2    = d_in[14];
  const void* b2    = d_in[15];
  const void* dw    = d_in[16];
  const void* db    = d_in[17];
  const void* vw1   = d_in[18];
  const void* vb1   = d_in[19];
  const void* vw2   = d_in[20];
  const void* vb2   = d_in[21];

  char* w0 = (char*)d_ws;
  char* w = w0;
  float* tr[2]; float* vi[2]; float* hd[2]; short* Xc[2];
  for (int i = 0; i < 2; ++i){ tr[i] = (float*)w; w += ((size_t)NROWS*2*4 + 255) & ~255ull; }
  for (int i = 0; i < 2; ++i){ vi[i] = (float*)w; w += ((size_t)NROWS*4   + 255) & ~255ull; }
  for (int i = 0; i < 2; ++i){ hd[i] = (float*)w; w += ((size_t)NROWS*DN*4 + 255) & ~255ull; }
  for (int i = 0; i < 2; ++i){ Xc[i] = (short*)w; w += ((size_t)NROWS*64*2 + 255) & ~255ull; }
  bf16* pwt = (bf16*)w;                     w += ((size_t)128*XPAD*2 + 255) & ~255ull;
  bf16* w1t = (bf16*)w;                     w += ((size_t)4*256*128*2 + 255) & ~255ull;
  bf16* w2t = (bf16*)w;                     w += ((size_t)4*128*256*2 + 255) & ~255ull;
  bf16* vw1t = (bf16*)w;                    w += ((size_t)64*128*2 + 255) & ~255ull;
  u16*  fmapT = (u16*)w;                    w += ((size_t)TN*HN*WN*CN*2 + 255) & ~255ull;

  bool fast = ((size_t)(w - w0) <= ws_size);

  int nbset = NB_TW + NB_INIT + (fast ? NB_TRANS : 0);
  k_setup<<<nbset, 256, 0, stream>>>(ct, query, fmap, pw, w1, w2, vw1,
      tr[0], vi[0], pwt, w1t, w2t, vw1t, fmapT);

  if (fast){
    for (int it = 0; it < 4; ++it){
      int a = it & 1, b = a ^ 1;
      if (it == 0)
        k_iter<1,1,1><<<256, 1024, 0, stream>>>(fmapT, query, fs, Xc[a], Xc[b],
            tr[a], tr[b], vi[a], vi[b], hd[a], hd[b],
            pwt, pb, ln1g, ln1b, cw, cb, ln2g, ln2b,
            w1t, b1, w2t, b2, dw, db, vw1t, vb1, vw2, vb2, d_out, 0);
      else
        k_iter<1,0,0><<<256, 1024, 0, stream>>>(fmapT, query, fs, Xc[a], Xc[b],
            tr[a], tr[b], vi[a], vi[b], hd[a], hd[b],
            pwt, pb, ln1g, ln1b, cw, cb, ln2g, ln2b,
            w1t, b1, w2t, b2, dw, db, vw1t, vb1, vw2, vb2, d_out, it == 3);
    }
  } else {
    for (int it = 0; it < 4; ++it){
      int a = it & 1, b = a ^ 1;
      k_corr<<<NROWS, 64, 0, stream>>>(fmap, query, fs, tr[a], Xc[0]);
      if (it == 0)
        k_iter<0,1,0><<<256, 1024, 0, stream>>>(fmapT, query, fs, Xc[0], Xc[1],
            tr[a], tr[b], vi[a], vi[b], hd[a], hd[b],
            pwt, pb, ln1g, ln1b, cw, cb, ln2g, ln2b,
            w1t, b1, w2t, b2, dw, db, vw1t, vb1, vw2, vb2, d_out, 0);
      else
        k_iter<0,0,0><<<256, 1024, 0, stream>>>(fmapT, query, fs, Xc[0], Xc[1],
            tr[a], tr[b], vi[a], vi[b], hd[a], hd[b],
            pwt, pb, ln1g, ln1b, cw, cb, ln2g, ln2b,
            w1t, b1, w2t, b2, dw, db, vw1t, vb1, vw2, vb2, d_out, it == 3);
    }
  }
}

// Round 15
// 305.936 us; speedup vs baseline: 1.0359x; 1.0359x over previous
//
#include <hip/hip_runtime.h>
#include <hip/hip_bf16.h>
#include <math.h>

#define QN 128
#define TN 48
#define CN 64
#define HN 96
#define WN 128
#define DN 128
#define KK 49
#define IN_DIM 276
#define XPAD 288
#define NROWS (QN*TN)
#define PI_F 3.14159265358979323846f

typedef __hip_bfloat16 bf16;
typedef unsigned short u16;
using bf16x8 = __attribute__((ext_vector_type(8))) short;
using f32x4  = __attribute__((ext_vector_type(4))) float;

__device__ inline float fixnan(float x){ return (x == x && fabsf(x) < 1e30f) ? x : 0.f; }

template<int MODE> __device__ inline float ld(const void* p, size_t i){
  if constexpr (MODE == 0) return ((const float*)p)[i];
  else {
    unsigned int u = ((const unsigned short*)p)[i];
    return __uint_as_float(u << 16);
  }
}

__device__ inline short f2b(float x){
  __hip_bfloat16 h = __float2bfloat16(x);
  return *reinterpret_cast<short*>(&h);
}
__device__ inline float b2f16(u16 u){ return __uint_as_float(((unsigned int)u) << 16); }

// inline dtype detect: 1 = bf16 buffers, 0 = f32 buffers. Wave-uniform, deterministic.
__device__ inline int detect_mode(const void* query){
  const u16* q = (const u16*)query;
  int lane = threadIdx.x & 63;
  float v = b2f16(q[lane]);
  float a = fabsf(v);
  unsigned long long m = __ballot(a > 1e-3f && a < 30.f);
  return (__popcll(m) >= 48) ? 1 : 0;
}

__device__ inline float waveReduceSum(float v){
  #pragma unroll
  for (int off = 32; off > 0; off >>= 1) v += __shfl_xor(v, off, 64);
  return v;
}

__device__ inline float gelu_exact(float x){
  return 0.5f * x * (1.f + erff(x * 0.70710678118654752440f));
}

__device__ inline f32x4 mfma16(bf16x8 a, bf16x8 b, f32x4 c){
  return __builtin_amdgcn_mfma_f32_16x16x32_bf16(a, b, c, 0, 0, 0);
}

__device__ inline float decode_stride(const void* p){
  int iv = *(const int*)p;
  if (iv >= 1 && iv <= (1 << 20)) return (float)iv;
  float fv = __int_as_float(iv);
  if (fv == fv && fv >= 0.25f && fv <= 1048576.f) return fv;
  unsigned int lo = ((unsigned int)(*(const unsigned short*)p)) << 16;
  float bv = __uint_as_float(lo);
  if (bv == bv && bv >= 0.25f && bv <= 1048576.f) return bv;
  return 4.f;
}

__device__ inline void bput(short* base, int stride_sh, int r, int k, float v){
  *(short*)((char*)base + (size_t)r*stride_sh*2 + ((2*k) ^ ((r & 7) << 4))) = f2b(v);
}
__device__ inline float bget(const short* base, int stride_sh, int r, int k){
  unsigned short u = *(const unsigned short*)((const char*)base + (size_t)r*stride_sh*2 + ((2*k) ^ ((r & 7) << 4)));
  return __uint_as_float(((unsigned int)u) << 16);
}
__device__ inline bf16x8 bget8(const short* base, int stride_sh, int r, int k0){
  return *(const bf16x8*)((const char*)base + (size_t)r*stride_sh*2 + ((2*k0) ^ ((r & 7) << 4)));
}

struct SLds {
  float sc0[32], sc1[32];
  float qv[CN];
  float hdl[32][132];
  union {
    short Xs[32][320];
    struct { short hn[32][128]; short hn2[32][128]; short y1[32][256]; } b;
    float dots[32][64];
  } u;
};

// ---- weight transpose sizes ----
#define TW_PW   (128*XPAD)
#define TW_W1   (4*256*128)
#define TW_W2   (4*128*256)
#define TW_VW1  (64*128)
#define TW_TOT  (TW_PW + TW_W1 + TW_W2 + TW_VW1)
#define NB_TW   ((TW_TOT + 255)/256)
#define NB_INIT ((NROWS + 255)/256)
#define NB_TRANS (TN*HN)

template<int MODE>
__device__ void transW_item(int idx, const void* pw, const void* w1, const void* w2,
                            const void* vw1,
                            bf16* pwt, bf16* w1t, bf16* w2t, bf16* vw1t){
  if (idx < TW_PW){
    int n = idx / XPAD, kk = idx % XPAD;
    float v = (kk < IN_DIM) ? ld<MODE>(pw, (size_t)kk*DN + n) : 0.f;
    ((short*)pwt)[idx] = f2b(v);
  } else if (idx < TW_PW + TW_W1){
    int i2 = idx - TW_PW;
    int k = i2 & 127, n = (i2 >> 7) & 255, l = i2 >> 15;
    ((short*)w1t)[i2] = f2b(ld<MODE>(w1, (size_t)l*32768 + (size_t)k*256 + n));
  } else if (idx < TW_PW + TW_W1 + TW_W2){
    int i3 = idx - TW_PW - TW_W1;
    int k = i3 & 255, n = (i3 >> 8) & 127, l = i3 >> 15;
    ((short*)w2t)[i3] = f2b(ld<MODE>(w2, (size_t)l*32768 + (size_t)k*128 + n));
  } else {
    int i4 = idx - TW_PW - TW_W1 - TW_W2;
    int n = i4 >> 7, k = i4 & 127;
    ((short*)vw1t)[i4] = f2b(ld<MODE>(vw1, (size_t)k*64 + n));
  }
}

template<int MODE>
__device__ void setup_body(u16 (*tile)[130], int bid,
    const void* ct, const void* query, const void* fmap,
    const void* pw, const void* w1, const void* w2, const void* vw1,
    float* tracks, float* vis_sum,
    bf16* pwt, bf16* w1t, bf16* w2t, bf16* vw1t, u16* fmapT){
  int tid = threadIdx.x;
  if (bid < NB_TW){
    int idx = bid*256 + tid;
    if (idx < TW_TOT) transW_item<MODE>(idx, pw, w1, w2, vw1, pwt, w1t, w2t, vw1t);
  } else if (bid < NB_TW + NB_INIT){
    int i = (bid - NB_TW)*256 + tid;
    if (i < NROWS){
      tracks[2*i]   = fixnan(ld<MODE>(ct, 2*i));
      tracks[2*i+1] = fixnan(ld<MODE>(ct, 2*i+1));
      vis_sum[i] = 0.f;
    }
  } else {
    int tb = bid - NB_TW - NB_INIT;
    int t = tb / HN, y = tb % HN;
    int wv = tid >> 6, lane = tid & 63;
    #pragma unroll 4
    for (int ci = 0; ci < 16; ++ci){
      int c = ci*4 + wv;
      size_t base = (((size_t)t*CN + c)*HN + y)*WN;
      if constexpr (MODE == 1){
        const u16* fp = (const u16*)fmap + base + 2*lane;
        tile[c][2*lane]   = fp[0];
        tile[c][2*lane+1] = fp[1];
      } else {
        const float* fp = (const float*)fmap + base + 2*lane;
        tile[c][2*lane]   = (u16)f2b(fp[0]);
        tile[c][2*lane+1] = (u16)f2b(fp[1]);
      }
    }
    __syncthreads();
    u16* op = fmapT + (((size_t)t*HN + y)*WN)*CN + lane;
    #pragma unroll 4
    for (int xi = 0; xi < 32; ++xi){
      int x = xi*4 + wv;
      op[(size_t)x*CN] = tile[lane][x];
    }
  }
}
__global__ __launch_bounds__(256) void k_setup(
    const void* ct, const void* query, const void* fmap,
    const void* pw, const void* w1, const void* w2, const void* vw1,
    float* tracks, float* vis_sum,
    bf16* pwt, bf16* w1t, bf16* w2t, bf16* vw1t, u16* fmapT){
  __shared__ u16 tile[64][130];
  if (detect_mode(query) == 0)
    setup_body<0>(tile, blockIdx.x, ct, query, fmap, pw, w1, w2, vw1,
                  tracks, vis_sum, pwt, w1t, w2t, vw1t, fmapT);
  else
    setup_body<1>(tile, blockIdx.x, ct, query, fmap, pw, w1, w2, vw1,
                  tracks, vis_sum, pwt, w1t, w2t, vw1t, fmapT);
}

// ==== standalone corr (seed / slow path) ====
template<int MODE, int FAST>
__device__ void corr_impl(float* qv, float* dots,
    const void* fmap, const u16* fmapT, const void* query, const void* stride_p,
    const float* __restrict__ tr, short* __restrict__ Xc)
{
  int blk = blockIdx.x;
  int q = blk / TN, t = blk % TN;
  int ll = threadIdx.x;
  qv[ll] = ld<MODE>(query, q*CN + ll);
  float fs = decode_stride(stride_p);
  float c0 = fixnan(tr[2*blk]), c1 = fixnan(tr[2*blk+1]);
  float px = fminf(fmaxf(c0 / fs, -1e6f), 1e6f);
  float py = fminf(fmaxf(c1 / fs, -1e6f), 1e6f);
  float fx0 = floorf(px), fy0 = floorf(py);
  float dx = px - fx0, dy = py - fy0;
  __syncthreads();

  if constexpr (FAST){
    float qv8[8];
    #pragma unroll
    for (int u = 0; u < 8; ++u) qv8[u] = qv[(ll & 7)*8 + u];
    int x0 = (int)fx0 - 3, y0 = (int)fy0 - 3;
    dots[ll] = 0.f;
    __syncthreads();
    if (x0 <= 127 && x0 + 7 >= 0){
      int x0c = min(max(x0, 0), WN - 8);
      int sh = x0c - x0;
      int i = (ll >> 3) + sh;
      bool wr = ((ll & 7) == 0) && (i >= 0) && (i < 8);
      #pragma unroll
      for (int j = 0; j < 8; ++j){
        int yj = y0 + j;
        if (yj < 0 || yj >= HN) continue;
        const u16* blkp = fmapT + ((((size_t)t*HN + yj)*WN + x0c) << 6);
        bf16x8 v = *(const bf16x8*)(blkp + ll*8);
        float p = 0.f;
        #pragma unroll
        for (int u = 0; u < 8; ++u) p += qv8[u] * b2f16((u16)v[u]);
        p += __shfl_xor(p, 1, 64);
        p += __shfl_xor(p, 2, 64);
        p += __shfl_xor(p, 4, 64);
        if (wr) dots[j*8 + i] = p;
      }
    }
  } else {
    int bx = (int)fx0, by = (int)fy0;
    int j = ll >> 3, i = ll & 7;
    int xi = bx + i - 3, yi = by + j - 3;
    float dot = 0.f;
    if (xi >= 0 && xi < WN && yi >= 0 && yi < HN){
      size_t base = ((size_t)t*CN)*HN*WN + (size_t)yi*WN + xi;
      #pragma unroll 8
      for (int c = 0; c < CN; ++c)
        dot += qv[c] * ld<MODE>(fmap, base + (size_t)c*HN*WN);
    }
    dots[j*8 + i] = dot;
  }
  __syncthreads();

  if (ll < KK){
    int oy = ll / 7, ox = ll % 7;
    float v = (1.f-dx)*(1.f-dy)*dots[oy*8+ox]   + dx*(1.f-dy)*dots[oy*8+ox+1]
            + (1.f-dx)*dy*dots[(oy+1)*8+ox]     + dx*dy*dots[(oy+1)*8+ox+1];
    Xc[(size_t)blk*64 + ll] = f2b(fixnan(v));
  }
}
template<int FAST>
__global__ __launch_bounds__(64) void k_corr(
    const void* fmap, const u16* fmapT, const void* query, const void* stride_p,
    const float* tr, short* Xc)
{
  __shared__ float qv[CN];
  __shared__ float dots[64];
  if (detect_mode(query) == 0) corr_impl<0, FAST>(qv, dots, fmap, fmapT, query, stride_p, tr, Xc);
  else                         corr_impl<1, FAST>(qv, dots, fmap, fmapT, query, stride_p, tr, Xc);
}

// ==== fused trunk: block=(q, t-half); 32 rows, 16 waves; optional corr tail ====
template<int MODE, int TAIL, int FIRST>
__device__ void iter_impl(SLds& s,
    const u16* __restrict__ fmapT, const void* query, const void* stride_p,
    const short* __restrict__ XcR, short* __restrict__ XcW,
    const float* __restrict__ tr_in, float* __restrict__ tr_out,
    const float* __restrict__ vi_in, float* __restrict__ vi_out,
    const float* __restrict__ hd_in, float* __restrict__ hd_out,
    const bf16* pwt, const void* pb,
    const void* ln1g, const void* ln1b, const void* cw, const void* cb,
    const void* ln2g, const void* ln2b,
    const bf16* w1t, const void* b1, const bf16* w2t, const void* b2,
    const void* dwp, const void* dbp,
    const bf16* vw1t, const void* vb1, const void* vw2, const void* vb2,
    void* out, int last)
{
  int bid = blockIdx.x;
  int q = bid >> 1, half = bid & 1, T0 = half * 16;
  int tid = threadIdx.x, wv = tid >> 6, ll = tid & 63;
  int R0 = q*TN + T0;
  float fs = decode_stride(stride_p);

  if (tid < 32){
    s.sc0[tid] = fixnan(tr_in[2*(R0 + tid)]);
    s.sc1[tid] = fixnan(tr_in[2*(R0 + tid) + 1]);
  }
  if (tid >= 64 && tid < 128) s.qv[tid - 64] = ld<MODE>(query, q*CN + (tid - 64));
  __syncthreads();

  // ---- assemble X ----
  for (int idx = tid; idx < 32*KK; idx += 1024){
    int r = idx / KK, kk = idx % KK;
    bput(&s.u.Xs[0][0], 320, r, kk, b2f16((u16)XcR[(size_t)(R0 + r)*64 + kk]));
  }
  for (int idx = tid; idx < 32*3; idx += 1024){
    int r = idx / 3, cd = idx % 3;
    float v = (cd == 0) ? s.sc0[r] : (cd == 1 ? s.sc1[r] : (float)(T0+r)/(float)(TN-1));
    bput(&s.u.Xs[0][0], 320, r, KK + cd, v);
  }
  for (int idx = tid; idx < 32*96; idx += 1024){
    int r = idx / 96, j = idx % 96, coord = j >> 5, rm = j & 31, band = rm & 15;
    float cv = (coord == 0) ? s.sc0[r] : (coord == 1 ? s.sc1[r] : (float)(T0+r)/(float)(TN-1));
    float a = cv * exp2f(0.6f*(float)band) * PI_F;
    float v = (rm < 16) ? __sinf(a) : __cosf(a);
    bput(&s.u.Xs[0][0], 320, r, KK + 3 + coord*32 + rm, fixnan(v));
  }
  if constexpr (FIRST){
    for (int idx = tid; idx < 32*DN; idx += 1024){
      int r = idx >> 7, d = idx & 127;
      bput(&s.u.Xs[0][0], 320, r, 148 + d, 0.f);
    }
  } else {
    for (int idx = tid; idx < 32*32; idx += 1024){
      int r = idx >> 5, d4 = (idx & 31)*4;
      f32x4 hv = *(const f32x4*)(hd_in + (size_t)(R0 + r)*DN + d4);
      #pragma unroll
      for (int u = 0; u < 4; ++u)
        bput(&s.u.Xs[0][0], 320, r, 148 + d4 + u, fixnan(hv[u]));
    }
  }
  for (int idx = tid; idx < 32*12; idx += 1024){
    int r = idx / 12, p = idx % 12;
    bput(&s.u.Xs[0][0], 320, r, IN_DIM + p, 0.f);
  }
  __syncthreads();

  // ---- proj MFMA: 1 tile/wave ----
  {
    int rA = ll & 15, gK = ll >> 4;
    int rt = wv & 1, nt = wv >> 1;
    bf16x8 afr[9];
    #pragma unroll
    for (int ks = 0; ks < 9; ++ks)
      afr[ks] = bget8(&s.u.Xs[0][0], 320, rt*16 + rA, ks*32 + gK*8);
    float bv = ld<MODE>(pb, nt*16 + rA);
    f32x4 acc = {bv, bv, bv, bv};
    #pragma unroll
    for (int ks = 0; ks < 9; ++ks)
      acc = mfma16(afr[ks],
        *(const bf16x8*)((const short*)pwt + (size_t)(nt*16 + rA)*XPAD + ks*32 + gK*8), acc);
    #pragma unroll
    for (int r2 = 0; r2 < 4; ++r2)
      s.hdl[rt*16 + gK*4 + r2][nt*16 + rA] = fixnan(acc[r2]);
  }

  // ---- 4 transformer blocks ----
  #pragma unroll 1
  for (int L = 0; L < 4; ++L){
    float cwr0[5], cwr1[5];
    #pragma unroll
    for (int k = 0; k < 5; ++k){
      cwr0[k] = ld<MODE>(cw, ((size_t)L*DN + ll)*5 + k);
      cwr1[k] = ld<MODE>(cw, ((size_t)L*DN + ll + 64)*5 + k);
    }
    float cbv0 = ld<MODE>(cb, L*DN + ll), cbv1 = ld<MODE>(cb, L*DN + ll + 64);
    float g20 = ld<MODE>(ln2g, L*DN + ll), g21 = ld<MODE>(ln2g, L*DN + ll + 64);
    float c20 = ld<MODE>(ln2b, L*DN + ll), c21 = ld<MODE>(ln2b, L*DN + ll + 64);
    __syncthreads();
    // LN1 -> hn
    {
      float g0 = ld<MODE>(ln1g, L*DN + ll), g1 = ld<MODE>(ln1g, L*DN + ll + 64);
      float b0 = ld<MODE>(ln1b, L*DN + ll), b1v = ld<MODE>(ln1b, L*DN + ll + 64);
      #pragma unroll
      for (int rr = 0; rr < 2; ++rr){
        int r = wv*2 + rr;
        float a0 = s.hdl[r][ll], a1 = s.hdl[r][ll+64];
        float su = waveReduceSum(a0 + a1);
        float sq = waveReduceSum(a0*a0 + a1*a1);
        float m = su * (1.f/128.f);
        float var = fmaxf(sq * (1.f/128.f) - m*m, 0.f);
        float inv = rsqrtf(var + 1e-5f);
        bput(&s.u.b.hn[0][0], 128, r, ll,      (a0 - m)*inv*g0 + b0);
        bput(&s.u.b.hn[0][0], 128, r, ll + 64, (a1 - m)*inv*g1 + b1v);
      }
    }
    __syncthreads();
    // conv + residual + LN2 (registers) -> hdl, hn2
    #pragma unroll
    for (int rr = 0; rr < 2; ++rr){
      int r = wv*2 + rr, t = T0 + r;
      float a0 = cbv0, a1 = cbv1;
      #pragma unroll
      for (int k = 0; k < 5; ++k){
        int tg = t + k - 2, tl = r + k - 2;
        if (tg >= 0 && tg < TN && tl >= 0 && tl < 32){
          a0 += bget(&s.u.b.hn[0][0], 128, tl, ll)      * cwr0[k];
          a1 += bget(&s.u.b.hn[0][0], 128, tl, ll + 64) * cwr1[k];
        }
      }
      float x0 = fixnan(s.hdl[r][ll] + a0);
      float x1 = fixnan(s.hdl[r][ll+64] + a1);
      s.hdl[r][ll] = x0; s.hdl[r][ll+64] = x1;
      float su = waveReduceSum(x0 + x1);
      float sq = waveReduceSum(x0*x0 + x1*x1);
      float m = su * (1.f/128.f);
      float var = fmaxf(sq * (1.f/128.f) - m*m, 0.f);
      float inv = rsqrtf(var + 1e-5f);
      bput(&s.u.b.hn2[0][0], 128, r, ll,      (x0 - m)*inv*g20 + c20);
      bput(&s.u.b.hn2[0][0], 128, r, ll + 64, (x1 - m)*inv*g21 + c21);
    }
    __syncthreads();
    // GEMM1: hn2 @ w1 -> gelu -> y1
    {
      int rA = ll & 15, gK = ll >> 4;
      int rt = wv & 1, nt0 = wv >> 1;
      const short* w1s = (const short*)w1t + (size_t)L*32768;
      bf16x8 afr[4];
      #pragma unroll
      for (int ks = 0; ks < 4; ++ks)
        afr[ks] = bget8(&s.u.b.hn2[0][0], 128, rt*16 + rA, ks*32 + gK*8);
      #pragma unroll
      for (int h = 0; h < 2; ++h){
        int nt = nt0 + h*8;
        float bv = ld<MODE>(b1, L*256 + nt*16 + rA);
        f32x4 acc = {bv, bv, bv, bv};
        #pragma unroll
        for (int ks = 0; ks < 4; ++ks)
          acc = mfma16(afr[ks],
            *(const bf16x8*)(w1s + (size_t)(nt*16 + rA)*DN + ks*32 + gK*8), acc);
        #pragma unroll
        for (int r2 = 0; r2 < 4; ++r2)
          bput(&s.u.b.y1[0][0], 256, rt*16 + gK*4 + r2, nt*16 + rA, gelu_exact(acc[r2]));
      }
    }
    __syncthreads();
    // GEMM2: y1 @ w2 + residual -> hdl (and hn as bf16 when L==3, feeding vis MFMA)
    {
      int rA = ll & 15, gK = ll >> 4;
      int rt = wv & 1, nt = wv >> 1;
      const short* w2s = (const short*)w2t + (size_t)L*32768;
      bf16x8 afr[8];
      #pragma unroll
      for (int ks = 0; ks < 8; ++ks)
        afr[ks] = bget8(&s.u.b.y1[0][0], 256, rt*16 + rA, ks*32 + gK*8);
      float bv = ld<MODE>(b2, L*DN + nt*16 + rA);
      f32x4 acc = {bv, bv, bv, bv};
      #pragma unroll
      for (int ks = 0; ks < 8; ++ks)
        acc = mfma16(afr[ks],
          *(const bf16x8*)(w2s + (size_t)(nt*16 + rA)*256 + ks*32 + gK*8), acc);
      #pragma unroll
      for (int r2 = 0; r2 < 4; ++r2){
        int r = rt*16 + gK*4 + r2, cc = nt*16 + rA;
        float x = fixnan(s.hdl[r][cc] + acc[r2]);
        s.hdl[r][cc] = x;
        if (L == 3) bput(&s.u.b.hn[0][0], 128, r, cc, x);
      }
    }
  }
  __syncthreads();

  // ---- heads: vis MFMA directly from hn (written by GEMM2 L=3) ----
  float* gC = (float*)&s.u.b.y1[0][0];   // [32][72] f32
  {
    int rA = ll & 15, gK = ll >> 4;
    int rt = wv & 1, nt = wv >> 1;
    if (nt < 4){
      float bv = ld<MODE>(vb1, nt*16 + rA);
      f32x4 acc = {bv, bv, bv, bv};
      #pragma unroll
      for (int ks = 0; ks < 4; ++ks)
        acc = mfma16(bget8(&s.u.b.hn[0][0], 128, rt*16 + rA, ks*32 + gK*8),
                     *(const bf16x8*)((const short*)vw1t + (size_t)(nt*16 + rA)*128 + ks*32 + gK*8), acc);
      #pragma unroll
      for (int r2 = 0; r2 < 4; ++r2)
        gC[(rt*16 + gK*4 + r2)*72 + nt*16 + rA] = gelu_exact(acc[r2]);
    }
  }
  __syncthreads();
  float vw2v = ld<MODE>(vw2, ll);
  float dwa = ld<MODE>(dwp, ll*2),     dwb = ld<MODE>(dwp, (ll+64)*2);
  float dwc = ld<MODE>(dwp, ll*2 + 1), dwd = ld<MODE>(dwp, (ll+64)*2 + 1);
  #pragma unroll
  for (int rr = 0; rr < 2; ++rr){
    int r = wv*2 + rr, t = T0 + r, grow = q*TN + t;
    bool owned = half ? (r >= 8) : (r < 24);
    float vis = waveReduceSum(gC[r*72 + ll] * vw2v);
    float x0 = s.hdl[r][ll], x1 = s.hdl[r][ll+64];
    float dX = waveReduceSum(x0*dwa + x1*dwb);
    float dY = waveReduceSum(x0*dwc + x1*dwd);
    if (owned){
      hd_out[(size_t)grow*DN + ll]      = fixnan(x0);
      hd_out[(size_t)grow*DN + ll + 64] = fixnan(x1);
      if (ll == 0){
        float tx = fixnan(tr_in[2*grow]   + dX + ld<MODE>(dbp, 0));
        float ty = fixnan(tr_in[2*grow+1] + dY + ld<MODE>(dbp, 1));
        tr_out[2*grow] = tx; tr_out[2*grow+1] = ty;
        s.sc0[r] = tx; s.sc1[r] = ty;
        float vs = fixnan(vi_in[grow] + vis + ld<MODE>(vb2, 0));
        vi_out[grow] = vs;
        if (last){
          if constexpr (MODE == 0){
            ((float*)out)[grow*3 + 0] = tx;
            ((float*)out)[grow*3 + 1] = ty;
            ((float*)out)[grow*3 + 2] = vs * 0.25f;
          } else {
            ((bf16*)out)[grow*3 + 0] = __float2bfloat16(tx);
            ((bf16*)out)[grow*3 + 1] = __float2bfloat16(ty);
            ((bf16*)out)[grow*3 + 2] = __float2bfloat16(vs * 0.25f);
          }
        }
      }
    }
  }

  // ---- tail corr for next iteration ----
  if constexpr (TAIL){
    if (!last){
      __syncthreads();
      float qv8[8];
      #pragma unroll
      for (int u = 0; u < 8; ++u) qv8[u] = s.qv[(ll & 7)*8 + u];
      #pragma unroll
      for (int rr = 0; rr < 2; ++rr){
        int r = wv*2 + rr, t = T0 + r, grow = q*TN + t;
        bool owned = half ? (r >= 8) : (r < 24);
        if (!owned) continue;
        float* dots = &s.u.dots[r][0];
        float px = fminf(fmaxf(s.sc0[r] / fs, -1e6f), 1e6f);
        float py = fminf(fmaxf(s.sc1[r] / fs, -1e6f), 1e6f);
        float fx0 = floorf(px), fy0 = floorf(py);
        float dx = px - fx0, dy = py - fy0;
        int x0 = (int)fx0 - 3, y0 = (int)fy0 - 3;
        dots[ll] = 0.f;
        if (x0 <= 127 && x0 + 7 >= 0){
          int x0c = min(max(x0, 0), WN - 8);
          int sh = x0c - x0;
          int i = (ll >> 3) + sh;
          bool wr = ((ll & 7) == 0) && (i >= 0) && (i < 8);
          #pragma unroll
          for (int j = 0; j < 8; ++j){
            int yj = y0 + j;
            if (yj < 0 || yj >= HN) continue;
            const u16* blkp = fmapT + ((((size_t)t*HN + yj)*WN + x0c) << 6);
            bf16x8 v = *(const bf16x8*)(blkp + ll*8);
            float p = 0.f;
            #pragma unroll
            for (int u = 0; u < 8; ++u) p += qv8[u] * b2f16((u16)v[u]);
            p += __shfl_xor(p, 1, 64);
            p += __shfl_xor(p, 2, 64);
            p += __shfl_xor(p, 4, 64);
            if (wr) dots[j*8 + i] = p;
          }
        }
        if (ll < KK){
          int oy = ll / 7, ox = ll % 7;
          float v = (1.f-dx)*(1.f-dy)*dots[oy*8+ox]   + dx*(1.f-dy)*dots[oy*8+ox+1]
                  + (1.f-dx)*dy*dots[(oy+1)*8+ox]     + dx*dy*dots[(oy+1)*8+ox+1];
          XcW[(size_t)grow*64 + ll] = f2b(fixnan(v));
        }
      }
    }
  }
}

template<int TAIL, int FIRST>
__global__ __launch_bounds__(1024, 1) void k_iter(
    const u16* fmapT, const void* query, const void* stride_p,
    const short* XcR, short* XcW,
    const float* tr_in, float* tr_out, const float* vi_in, float* vi_out,
    const float* hd_in, float* hd_out,
    const bf16* pwt, const void* pb,
    const void* ln1g, const void* ln1b, const void* cw, const void* cb,
    const void* ln2g, const void* ln2b,
    const bf16* w1t, const void* b1, const bf16* w2t, const void* b2,
    const void* dwp, const void* dbp,
    const bf16* vw1t, const void* vb1, const void* vw2, const void* vb2,
    void* out, int last)
{
  __shared__ SLds s;
  if (detect_mode(query) == 0)
    iter_impl<0, TAIL, FIRST>(s, fmapT, query, stride_p, XcR, XcW, tr_in, tr_out, vi_in, vi_out,
                 hd_in, hd_out, pwt, pb, ln1g, ln1b, cw, cb, ln2g, ln2b, w1t, b1, w2t, b2,
                 dwp, dbp, vw1t, vb1, vw2, vb2, out, last);
  else
    iter_impl<1, TAIL, FIRST>(s, fmapT, query, stride_p, XcR, XcW, tr_in, tr_out, vi_in, vi_out,
                 hd_in, hd_out, pwt, pb, ln1g, ln1b, cw, cb, ln2g, ln2b, w1t, b1, w2t, b2,
                 dwp, dbp, vw1t, vb1, vw2, vb2, out, last);
}

extern "C" void kernel_launch(void* const* d_in, const int* in_sizes, int n_in,
                              void* d_out, int out_size, void* d_ws, size_t ws_size,
                              hipStream_t stream) {
  const void* ct    = d_in[0];
  const void* query = d_in[1];
  const void* fmap  = d_in[2];
  const void* fs    = d_in[3];
  const void* pw    = d_in[4];
  const void* pb    = d_in[5];
  const void* ln1g  = d_in[6];
  const void* ln1b  = d_in[7];
  const void* cw    = d_in[8];
  const void* cb    = d_in[9];
  const void* ln2g  = d_in[10];
  const void* ln2b  = d_in[11];
  const void* w1    = d_in[12];
  const void* b1    = d_in[13];
  const void* w2    = d_in[14];
  const void* b2    = d_in[15];
  const void* dw    = d_in[16];
  const void* db    = d_in[17];
  const void* vw1   = d_in[18];
  const void* vb1   = d_in[19];
  const void* vw2   = d_in[20];
  const void* vb2   = d_in[21];

  char* w0 = (char*)d_ws;
  char* w = w0;
  float* tr[2]; float* vi[2]; float* hd[2]; short* Xc[2];
  for (int i = 0; i < 2; ++i){ tr[i] = (float*)w; w += ((size_t)NROWS*2*4 + 255) & ~255ull; }
  for (int i = 0; i < 2; ++i){ vi[i] = (float*)w; w += ((size_t)NROWS*4   + 255) & ~255ull; }
  for (int i = 0; i < 2; ++i){ hd[i] = (float*)w; w += ((size_t)NROWS*DN*4 + 255) & ~255ull; }
  for (int i = 0; i < 2; ++i){ Xc[i] = (short*)w; w += ((size_t)NROWS*64*2 + 255) & ~255ull; }
  bf16* pwt = (bf16*)w;                     w += ((size_t)128*XPAD*2 + 255) & ~255ull;
  bf16* w1t = (bf16*)w;                     w += ((size_t)4*256*128*2 + 255) & ~255ull;
  bf16* w2t = (bf16*)w;                     w += ((size_t)4*128*256*2 + 255) & ~255ull;
  bf16* vw1t = (bf16*)w;                    w += ((size_t)64*128*2 + 255) & ~255ull;
  u16*  fmapT = (u16*)w;                    w += ((size_t)TN*HN*WN*CN*2 + 255) & ~255ull;

  bool fast = ((size_t)(w - w0) <= ws_size);

  int nbset = NB_TW + NB_INIT + (fast ? NB_TRANS : 0);
  k_setup<<<nbset, 256, 0, stream>>>(ct, query, fmap, pw, w1, w2, vw1,
      tr[0], vi[0], pwt, w1t, w2t, vw1t, fmapT);

  if (fast){
    k_corr<1><<<NROWS, 64, 0, stream>>>(fmap, fmapT, query, fs, tr[0], Xc[0]);
    for (int it = 0; it < 4; ++it){
      int a = it & 1, b = a ^ 1;
      if (it == 0)
        k_iter<1,1><<<256, 1024, 0, stream>>>(fmapT, query, fs, Xc[a], Xc[b],
            tr[a], tr[b], vi[a], vi[b], hd[a], hd[b],
            pwt, pb, ln1g, ln1b, cw, cb, ln2g, ln2b,
            w1t, b1, w2t, b2, dw, db, vw1t, vb1, vw2, vb2, d_out, 0);
      else
        k_iter<1,0><<<256, 1024, 0, stream>>>(fmapT, query, fs, Xc[a], Xc[b],
            tr[a], tr[b], vi[a], vi[b], hd[a], hd[b],
            pwt, pb, ln1g, ln1b, cw, cb, ln2g, ln2b,
            w1t, b1, w2t, b2, dw, db, vw1t, vb1, vw2, vb2, d_out, it == 3);
    }
  } else {
    for (int it = 0; it < 4; ++it){
      int a = it & 1, b = a ^ 1;
      k_corr<0><<<NROWS, 64, 0, stream>>>(fmap, fmapT, query, fs, tr[a], Xc[0]);
      if (it == 0)
        k_iter<0,1><<<256, 1024, 0, stream>>>(fmapT, query, fs, Xc[0], Xc[1],
            tr[a], tr[b], vi[a], vi[b], hd[a], hd[b],
            pwt, pb, ln1g, ln1b, cw, cb, ln2g, ln2b,
            w1t, b1, w2t, b2, dw, db, vw1t, vb1, vw2, vb2, d_out, 0);
      else
        k_iter<0,0><<<256, 1024, 0, stream>>>(fmapT, query, fs, Xc[0], Xc[1],
            tr[a], tr[b], vi[a], vi[b], hd[a], hd[b],
            pwt, pb, ln1g, ln1b, cw, cb, ln2g, ln2b,
            w1t, b1, w2t, b2, dw, db, vw1t, vb1, vw2, vb2, d_out, it == 3);
    }
  }
}